// Round 7
// baseline (125.080 us; speedup 1.0000x reference)
//
#include <hip/hip_runtime.h>
#include <math.h>

#define HW    16384
#define NTOK  32768
#define CDIM  128
#define HFDIM 512
#define NEXP  6

typedef __attribute__((ext_vector_type(8))) short short8;
typedef __attribute__((ext_vector_type(8))) unsigned short ushort8v;
typedef __attribute__((ext_vector_type(16))) float f32x16;
typedef unsigned long long u64;

// workspace byte offsets (256-aligned)
#define OFF_XFB    0UL          // N*128 bf16      = 8,388,608
#define OFF_LIST   8388608UL    // E*N int         =   786,432
#define OFF_GATES  9175040UL    // 2N float        =   262,144
#define OFF_OUTBUF 9437184UL    // 2N*128 bf16     = 16,777,216
#define OFF_WT1    42991616UL   // E*4*16384 bf16  =   786,432
#define OFF_WT2    43778048UL   // E*4*16384 bf16  =   786,432
#define OFF_BIAS   44564480UL
#define OFF_CNT    44564736UL
#define OFF_WSUM   44564992UL

__device__ __forceinline__ unsigned int bf16_1(float f) {
    unsigned int u = __float_as_uint(f);
    return (u + 0x7FFFu + ((u >> 16) & 1)) >> 16;
}
__device__ __forceinline__ unsigned int bf16pair(float lo, float hi) {
    return bf16_1(lo) | (bf16_1(hi) << 16);
}
// sigmoid-form gelu: x*sigmoid(1.702x); ~5 VALU inst
__device__ __forceinline__ float gelu_f(float v) {
    return __fdividef(v, 1.0f + __expf(-1.702f * v));
}
__device__ __forceinline__ short8 mk8(unsigned a, unsigned b, unsigned c, unsigned d) {
    union { unsigned u[4]; short8 s; } x;
    x.u[0] = a; x.u[1] = b; x.u[2] = c; x.u[3] = d;
    return x.s;
}

#define GLDS16(src, dst) __builtin_amdgcn_global_load_lds( \
    (const __attribute__((address_space(1))) void*)(src),  \
    (__attribute__((address_space(3))) void*)(dst), 16, 0, 0)

__device__ __forceinline__ f32x16 MFMA_B(short8 a, short8 b, f32x16 c) {
    return __builtin_amdgcn_mfma_f32_32x32x16_bf16(a, b, c, 0, 0, 0);
}

// K0: per-batch gating bias + zero atomics (deterministic per call)
__global__ __launch_bounds__(64) void prep_kernel(
    const float* __restrict__ prompt, const float* __restrict__ de_cls,
    const float* __restrict__ w_g, const float* __restrict__ gate_boost,
    const float* __restrict__ degra_w, const float* __restrict__ degra_b,
    float* __restrict__ bias, int* __restrict__ cnt, float* __restrict__ wsum)
{
    int t = threadIdx.x;
    if (t < 2 * NEXP) {
        int b = t / NEXP, e = t % NEXP;
        float acc = 0.f;
        for (int c = 0; c < CDIM; ++c)
            acc = fmaf(prompt[b*CDIM + c], w_g[(CDIM + c)*NEXP + e], acc);
        float db = 0.f;
        for (int d = 0; d < 6; ++d)
            db = fmaf(de_cls[b*6 + d], degra_w[d*NEXP + e], db);
        bias[b*NEXP + e] = acc + gate_boost[0] * (db + degra_b[e]);
    }
    if (t >= 32 && t < 32 + NEXP) cnt[t - 32] = 0;
    if (t >= 40 && t < 40 + NEXP) wsum[t - 40] = 0.f;
}

// Kw: fp32 weights -> bf16, transposed + pre-swizzled so LINEAR global_load_lds
// copies yield the swizzled LDS image.
// wt1: [e][g=hf/128][hf 128][k=C 128]   rows 256B, 16-slot XOR (hf&15)
// wt2: [e][g=hf/128][c 128][k=hf 128]   rows 256B, 16-slot XOR (c&15)
__global__ __launch_bounds__(256) void wconv_kernel(
    const float* __restrict__ fc1_w, const float* __restrict__ fc2_w,
    unsigned short* __restrict__ wt1, unsigned short* __restrict__ wt2)
{
    __shared__ unsigned short ls[128][128];   // [k][col] bf16, 32 KB
    const int bid = blockIdx.x;               // e*8 + which*4 + group
    const int e = bid >> 3, which = (bid >> 2) & 1, ch = bid & 3;
    const int t = threadIdx.x;
    #pragma unroll 4
    for (int i = 0; i < 16; ++i) {
        int id = t + 256 * i;                 // 4096 float4 tasks
        int k = id >> 5, q = id & 31;
        // which=0: ls[k=C][col=hf]  from fc1_w[e][k][ch*128+col]
        // which=1: ls[k=hf][col=c]  from fc2_w[e][ch*128+k][col]
        const float* p = which
            ? (fc2_w + (size_t)e*65536 + (size_t)(ch*128 + k)*128 + q*4)
            : (fc1_w + (size_t)e*65536 + (size_t)k*512 + ch*128 + q*4);
        float4 v = *(const float4*)p;
        u64 pk = (u64)bf16_1(v.x) | ((u64)bf16_1(v.y) << 16)
               | ((u64)bf16_1(v.z) << 32) | ((u64)bf16_1(v.w) << 48);
        *(u64*)&ls[k][q*4] = pk;
    }
    __syncthreads();
    unsigned short* dst = (which ? wt2 : wt1) + (((size_t)(e*4 + ch)) << 14);
    #pragma unroll 2
    for (int i = 0; i < 8; ++i) {
        int id = t + 256 * i;                 // 2048 tasks: (col, kg)
        int col = id & 127, kg = id >> 7;     // kg = k-group of 8 (0..15)
        unsigned short v[8];
        #pragma unroll
        for (int j = 0; j < 8; ++j) v[j] = ls[kg*8 + j][col];
        int4 pk;
        pk.x = v[0] | (v[1] << 16); pk.y = v[2] | (v[3] << 16);
        pk.z = v[4] | (v[5] << 16); pk.w = v[6] | (v[7] << 16);
        *(int4*)(dst + (size_t)col*128 + (((kg ^ (col & 15)) & 15) << 3)) = pk;
    }
}

// K1: transpose x -> xfb (token-major bf16), gating, top-2 softmax, lists.
__global__ __launch_bounds__(256) void gate_kernel(
    const float* __restrict__ x, const float* __restrict__ w_g,
    const float* __restrict__ bias, unsigned short* __restrict__ xfb,
    int* __restrict__ list, float* __restrict__ gates,
    int* __restrict__ cnt, float* __restrict__ wsum)
{
    __shared__ float xs[CDIM][65];
    __shared__ float wgs[CDIM][NEXP];
    __shared__ int   cnt_s[NEXP];
    __shared__ float ws_s[NEXP];
    __shared__ int   base_s[NEXP];
    const int t = threadIdx.x;
    const int n0 = blockIdx.x * 64;
    const int b = n0 >> 14;
    const int hw0 = n0 & (HW - 1);

    for (int i = t; i < CDIM * NEXP; i += 256) wgs[i / NEXP][i % NEXP] = w_g[i];
    if (t < NEXP) { cnt_s[t] = 0; ws_s[t] = 0.f; }

    const float* xb = x + (size_t)b * CDIM * HW + hw0;
    #pragma unroll 4
    for (int i = 0; i < 32; ++i) {
        int idx = t + 256 * i;
        int c = idx >> 6, j = idx & 63;
        xs[c][j] = xb[(size_t)c * HW + j];
    }
    __syncthreads();
    unsigned int* xo = (unsigned int*)xfb;
    #pragma unroll 4
    for (int i = 0; i < 16; ++i) {
        int idx = t + 256 * i;
        int tk = idx >> 6, cp = idx & 63;
        xo[(size_t)(n0 + tk) * 64 + cp] = bf16pair(xs[2*cp][tk], xs[2*cp+1][tk]);
    }

    int i0 = 0, i1 = 0, s0 = 0, s1 = 0;
    float g0 = 0.f, g1 = 0.f;
    if (t < 64) {
        float lg[NEXP];
        #pragma unroll
        for (int e = 0; e < NEXP; ++e) lg[e] = bias[b*NEXP + e];
        for (int c = 0; c < CDIM; ++c) {
            float xv = xs[c][t];
            #pragma unroll
            for (int e = 0; e < NEXP; ++e) lg[e] = fmaf(xv, wgs[c][e], lg[e]);
        }
        i0 = 0;
        #pragma unroll
        for (int e = 1; e < NEXP; ++e) if (lg[e] > lg[i0]) i0 = e;
        i1 = (i0 == 0) ? 1 : 0;
        #pragma unroll
        for (int e = 0; e < NEXP; ++e) if (e != i0 && lg[e] > lg[i1]) i1 = e;
        float e1 = expf(lg[i1] - lg[i0]);
        g0 = 1.f / (1.f + e1);
        g1 = e1 * g0;
        s0 = atomicAdd(&cnt_s[i0], 1);
        s1 = atomicAdd(&cnt_s[i1], 1);
        atomicAdd(&ws_s[i0], g0);
        atomicAdd(&ws_s[i1], g1);
    }
    __syncthreads();
    if (t < NEXP) {
        base_s[t] = atomicAdd(&cnt[t], cnt_s[t]);
        atomicAdd(&wsum[t], ws_s[t]);
    }
    __syncthreads();
    if (t < 64) {
        int n = n0 + t;
        list[i0 * NTOK + base_s[i0] + s0] = 2 * n;
        list[i1 * NTOK + base_s[i1] + s1] = 2 * n + 1;
        gates[2 * n]     = g0;
        gates[2 * n + 1] = g1;
    }
}

// K2: balance loss
__global__ void loss_kernel(const int* __restrict__ cnt,
                            const float* __restrict__ wsum,
                            float* __restrict__ out_loss)
{
    if (threadIdx.x == 0 && blockIdx.x == 0) {
        float mw = 0.f, mc = 0.f;
        for (int e = 0; e < NEXP; ++e) { mw += wsum[e]; mc += (float)cnt[e]; }
        mw /= NEXP; mc /= NEXP;
        float vw = 0.f, vc = 0.f;
        for (int e = 0; e < NEXP; ++e) {
            float dw = wsum[e] - mw, dc = (float)cnt[e] - mc;
            vw += dw * dw; vc += dc * dc;
        }
        vw /= (NEXP - 1); vc /= (NEXP - 1);
        out_loss[0] = vw / (mw * mw + 1e-10f) + vc / (mc * mc + 1e-10f);
    }
}

// K3: MFMA expert MLP, hid never touches LDS.
// 128-token blocks, 4 waves (32 tok each). Swapped GEMM1:
//   C1[hf][tok] = mfma(A=W1 frag (row=hf), B=X frag (col=tok))
// so lanes l and l^32 hold the SAME token column with complementary hf rows;
// bias+gelu in regs, pack bf16 pairs, 4x shfl_xor(32) assemble GEMM2's
// A-fragments (row=tok, k=hf) in-register. GEMM2 B = W2 [c][k=hf] from LDS.
// Weights staged per 128-hf group: 32KB W1 + 32KB W2, all reads 2-way (free).
// LDS 64 KB -> 2 blocks/CU (cross-block overlap hides stage/drain).
__global__ __launch_bounds__(256, 2) void expert_kernel(
    const unsigned short* __restrict__ xfb, const int* __restrict__ list,
    const int* __restrict__ cnt, const float* __restrict__ gates,
    const unsigned short* __restrict__ wt1, const unsigned short* __restrict__ wt2,
    const float* __restrict__ fc1_b, const float* __restrict__ fc2_b,
    unsigned short* __restrict__ outbuf)
{
    __shared__ unsigned short w1c[16384];  // 32 KB [128 hf][128 k] swz16
    __shared__ unsigned short w2c[16384];  // 32 KB [128 c][128 k=hf] swz16
    const int e = blockIdx.x;
    const int ne = cnt[e];
    const int base = blockIdx.y * 128;
    if (base >= ne) return;
    const int t = threadIdx.x;
    const int w = t >> 6, l = t & 63;
    const int l31 = l & 31, lk = (l >> 5) * 8;
    const bool islo = (l < 32);

    // wave w owns tokens base + w*32 .. +31; both lane-halves load same entry
    int r = base + w*32 + l31;
    int a = (r < ne) ? list[e*NTOK + r] : -1;
    float g = (a >= 0) ? gates[a] : 0.f;
    int tok = (a >= 0) ? (a >> 1) : 0;

    // X B-fragments from global: lane holds X[k=lk+ks*16..+7][tok=l31]
    short8 afr[8];
    {
        const unsigned short* xr = xfb + (size_t)tok*128 + lk;
        #pragma unroll
        for (int ks = 0; ks < 8; ++ks)
            afr[ks] = *(const short8*)(xr + ks*16);
    }

    f32x16 zz;
    #pragma unroll
    for (int i = 0; i < 16; ++i) zz[i] = 0.0f;
    f32x16 oacc[4] = {zz, zz, zz, zz};

    for (int gp = 0; gp < 4; ++gp) {
        // stage W1 group + W2 group (linear copy of pre-swizzled image)
        {
            const unsigned short* s1 = wt1 + (((size_t)(e*4 + gp)) << 14) + w*4096 + l*8;
            const unsigned short* s2 = wt2 + (((size_t)(e*4 + gp)) << 14) + w*4096 + l*8;
            #pragma unroll
            for (int i = 0; i < 8; ++i)
                GLDS16(s1 + i*512, &w1c[w*4096 + i*512]);
            #pragma unroll
            for (int i = 0; i < 8; ++i)
                GLDS16(s2 + i*512, &w2c[w*4096 + i*512]);
        }
        __syncthreads();

        short8 pa[8];   // GEMM2 A-frags for this group's 128 hf (8 k-groups)
        #pragma unroll
        for (int ch = 0; ch < 4; ++ch) {
            // GEMM1: C1[hf 32][tok 32], k = C = 128
            f32x16 c1 = zz;
            int arow = ch*32 + l31;
            #pragma unroll
            for (int ks = 0; ks < 8; ++ks) {
                int k = ks*16 + lk;
                short8 wf = *(const short8*)((const char*)w1c + arow*256
                             + ((((k >> 3) ^ (arow & 15)) & 15) << 4));
                c1 = MFMA_B(wf, afr[ks], c1);
            }
            // bias: reg rr -> hf_in_chunk = (rr&3) + 8*(rr>>2) + 4*(l>>5)
            const float* bb = fc1_b + (size_t)e*HFDIM + gp*128 + ch*32 + 4*(l >> 5);
            float4 b0 = *(const float4*)(bb);
            float4 b1 = *(const float4*)(bb + 8);
            float4 b2 = *(const float4*)(bb + 16);
            float4 b3 = *(const float4*)(bb + 24);
            float bias[16] = {b0.x, b0.y, b0.z, b0.w, b1.x, b1.y, b1.z, b1.w,
                              b2.x, b2.y, b2.z, b2.w, b3.x, b3.y, b3.z, b3.w};
            // gelu + pack adjacent-hf pairs
            unsigned int pr[8];
            #pragma unroll
            for (int i = 0; i < 8; ++i) {
                float h0 = gelu_f(c1[2*i]     + bias[2*i]);
                float h1 = gelu_f(c1[2*i + 1] + bias[2*i + 1]);
                pr[i] = bf16pair(h0, h1);
            }
            // cross-half exchange: low lanes need partner's hf{4..7},{20..23};
            // high lanes need partner's hf{8..11},{24..27} (same tok column)
            unsigned int rx0 = __shfl_xor(islo ? pr[2] : pr[0], 32);
            unsigned int rx1 = __shfl_xor(islo ? pr[3] : pr[1], 32);
            unsigned int rx2 = __shfl_xor(islo ? pr[6] : pr[4], 32);
            unsigned int rx3 = __shfl_xor(islo ? pr[7] : pr[5], 32);
            pa[2*ch]     = mk8(islo ? pr[0] : rx0, islo ? pr[1] : rx1,
                               islo ? rx0 : pr[2], islo ? rx1 : pr[3]);
            pa[2*ch + 1] = mk8(islo ? pr[4] : rx2, islo ? pr[5] : rx3,
                               islo ? rx2 : pr[6], islo ? rx3 : pr[7]);
        }
        // GEMM2: out[tok 32][c 128] += hid(group) x W2(group), k = 128 hf
        #pragma unroll
        for (int kg = 0; kg < 8; ++kg) {
            #pragma unroll
            for (int ct = 0; ct < 4; ++ct) {
                int crow = ct*32 + l31;
                short8 bf = *(const short8*)((const char*)w2c + crow*256
                             + ((((kg*2 + (l >> 5)) ^ (crow & 15)) & 15) << 4));
                oacc[ct] = MFMA_B(pa[kg], bf, oacc[ct]);
            }
        }
        __syncthreads();   // all LDS reads done -> safe to restage
    }

    // epilogue: gate * exp(out + fc2_b) -> bf16 scatter to outbuf[a]
    float bc[4];
    #pragma unroll
    for (int ct = 0; ct < 4; ++ct)
        bc[ct] = fc2_b[(size_t)e*CDIM + ct*32 + l31];
    #pragma unroll
    for (int rr = 0; rr < 16; ++rr) {
        int crow = (rr & 3) + 8*(rr >> 2) + 4*(l >> 5);
        int av   = __shfl(a, crow);
        float gv = __shfl(g, crow);
        if (av < 0) continue;
        unsigned short* po = outbuf + (size_t)av*CDIM + l31;
        #pragma unroll
        for (int ct = 0; ct < 4; ++ct)
            po[ct*32] = (unsigned short)bf16_1(gv * __expf(oacc[ct][rr] + bc[ct]));
    }
}

// K4: y = log(p0 + p1) from bf16 partials, transpose back to (B,C,H,W)
__global__ __launch_bounds__(256) void combine_kernel(
    const unsigned short* __restrict__ outbuf, float* __restrict__ out)
{
    __shared__ float ys[64][129];
    const int t = threadIdx.x;
    const int n0 = blockIdx.x * 64;
    const int b = n0 >> 14;
    const int hw0 = n0 & (HW - 1);
    #pragma unroll
    for (int i = 0; i < 4; ++i) {
        int idx = t + 256 * i;            // 1024 tasks: token x 16-col group
        int tk = idx >> 4, c8 = (idx & 15) * 8;
        const unsigned short* p = outbuf + (size_t)(n0 + tk) * 256 + c8;
        ushort8v p0 = *(const ushort8v*)p;
        ushort8v p1 = *(const ushort8v*)(p + 128);
        const float EPSL = 2.2204460492503131e-16f;
        #pragma unroll
        for (int j = 0; j < 8; ++j) {
            float v = __uint_as_float((unsigned)p0[j] << 16)
                    + __uint_as_float((unsigned)p1[j] << 16);
            ys[tk][c8 + j] = __logf(v == 0.f ? EPSL : v);
        }
    }
    __syncthreads();
    float* ob = out + (size_t)b * CDIM * HW + hw0;
    #pragma unroll 4
    for (int i = 0; i < 32; ++i) {
        int idx = t + 256 * i;
        int c = idx >> 6;
        int j = idx & 63;
        ob[(size_t)c * HW + j] = ys[j][c];
    }
}

extern "C" void kernel_launch(void* const* d_in, const int* in_sizes, int n_in,
                              void* d_out, int out_size, void* d_ws, size_t ws_size,
                              hipStream_t stream)
{
    const float* x       = (const float*)d_in[0];
    const float* prompt  = (const float*)d_in[1];
    const float* de_cls  = (const float*)d_in[2];
    const float* w_g     = (const float*)d_in[3];
    const float* gboost  = (const float*)d_in[4];
    const float* degra_w = (const float*)d_in[5];
    const float* degra_b = (const float*)d_in[6];
    const float* fc1_w   = (const float*)d_in[7];
    const float* fc1_b   = (const float*)d_in[8];
    const float* fc2_w   = (const float*)d_in[9];
    const float* fc2_b   = (const float*)d_in[10];
    float* out = (float*)d_out;
    char* ws = (char*)d_ws;

    unsigned short* xfb  = (unsigned short*)(ws + OFF_XFB);
    int*   list   = (int*)(ws + OFF_LIST);
    float* gates  = (float*)(ws + OFF_GATES);
    unsigned short* outbuf = (unsigned short*)(ws + OFF_OUTBUF);
    unsigned short* wt1 = (unsigned short*)(ws + OFF_WT1);
    unsigned short* wt2 = (unsigned short*)(ws + OFF_WT2);
    float* bias   = (float*)(ws + OFF_BIAS);
    int*   cnt    = (int*)(ws + OFF_CNT);
    float* wsum   = (float*)(ws + OFF_WSUM);

    prep_kernel<<<1, 64, 0, stream>>>(prompt, de_cls, w_g, gboost, degra_w,
                                      degra_b, bias, cnt, wsum);
    wconv_kernel<<<48, 256, 0, stream>>>(fc1_w, fc2_w, wt1, wt2);
    gate_kernel<<<512, 256, 0, stream>>>(x, w_g, bias, xfb, list, gates, cnt, wsum);
    loss_kernel<<<1, 64, 0, stream>>>(cnt, wsum, out + (size_t)NTOK * CDIM);
    dim3 eg(NEXP, 256);   // 128-token tiles; covers ne up to 32768
    expert_kernel<<<eg, 256, 0, stream>>>(xfb, list, cnt, gates, wt1, wt2,
                                          fc1_b, fc2_b, outbuf);
    combine_kernel<<<512, 256, 0, stream>>>(outbuf, out);
}